// Round 11
// baseline (304.336 us; speedup 1.0000x reference)
//
#include <hip/hip_runtime.h>
#include <math.h>

// N=131072 rows, K=1000 classes, f fp32 ~ N(0,1).
// out[0] = final_loss, out[1..K] = weighted[K]  (fp32)
//
// lse_i = log(sum_j exp(f_ij))   [no max subtraction: |f| <= ~6, exp<=~400, safe fp32]
// w_i   = ccp[l_i]/counts[l_i];  S = sum_i w_i*lse_i
// g[j]  = sum_i w_i*f[i,j];      d[k] = sum_{l_i=k}(lse_i - f[i,k])
// loss_vector[j] = S - g[j] - (K-1)*ccp[j]*d[j]/counts[j]
// final_loss = sum_j lv[j]; weighted[j] = counts[j]*lv[j]
//
// R11 = R6 canonical hot loop (wprep-prefetched w, strided rows, 3-deep
// pipeline, nt loads) + finalize folded into main as last-block-done tail.
// Lesson from R8/R10: per-row dependent lookups (vector OR scalar) inside the
// loop serialize against the row-load pipeline -- keep w in w_row (wprep).

typedef float f4 __attribute__((ext_vector_type(4)));

__device__ inline float wave_reduce_sum(float v) {
    #pragma unroll
    for (int off = 32; off > 0; off >>= 1)
        v += __shfl_xor(v, off, 64);
    return v;
}

// ---------------- kernel 1: per-class counts ----------------
__global__ __launch_bounds__(256) void count_kernel(const int* __restrict__ labels,
                                                    float* __restrict__ counts,
                                                    int N, int K) {
    __shared__ int h[1024];
    for (int j = threadIdx.x; j < 1024; j += blockDim.x) h[j] = 0;
    __syncthreads();
    for (int i = blockIdx.x * blockDim.x + threadIdx.x; i < N;
         i += gridDim.x * blockDim.x) {
        atomicAdd(&h[labels[i]], 1);
    }
    __syncthreads();
    for (int j = threadIdx.x; j < K; j += blockDim.x) {
        int c = h[j];
        if (c) atomicAdd(&counts[j], (float)c);
    }
}

// ---------------- kernel 2: per-row weight w[i] = ccp[l]/counts[l] ----------------
__global__ __launch_bounds__(256) void wprep_kernel(const int* __restrict__ labels,
                                                    const float* __restrict__ ccp,
                                                    const float* __restrict__ counts,
                                                    float* __restrict__ w_row, int N) {
    int i = blockIdx.x * blockDim.x + threadIdx.x;
    if (i < N) {
        int l = labels[i];
        w_row[i] = ccp[l] / counts[l];
    }
}

// ---------------- kernel 3: main streaming pass + tail finalize ----------------
template <int V4>
__global__ __launch_bounds__(256) void main_kernel(
    const float* __restrict__ f, const int* __restrict__ labels,
    const float* __restrict__ w_row, const float* __restrict__ ccp,
    const float* __restrict__ counts,
    float* __restrict__ g_multi, float* __restrict__ d_multi,
    float* __restrict__ S_acc, int* __restrict__ done_ctr,
    float* __restrict__ out, int N, int K) {
    __shared__ float g_sh[1024];
    __shared__ float d_sh[1024];
    __shared__ float s_sh[4];
    __shared__ float red[4];
    __shared__ int is_last;

    const int tid = threadIdx.x;
    const int lane = tid & 63;
    const int wid = tid >> 6;
    const int gwid = blockIdx.x * 4 + wid;
    const int nwaves = gridDim.x * 4;
    const int K4 = K >> 2;  // K % 4 == 0

    for (int j = tid; j < 1024; j += 256) { g_sh[j] = 0.f; d_sh[j] = 0.f; }
    __syncthreads();

    f4 gacc[V4];
    #pragma unroll
    for (int t = 0; t < V4; ++t) gacc[t] = (f4)(0.f);
    float s_reg = 0.f;  // lane 0: sum of w*lse over this wave's rows

    f4 valsA[V4], valsB[V4], valsC[V4];
    float wA = 0.f, wB = 0.f, wC = 0.f;
    int lA = 0, lB = 0, lC = 0;

    // issue loads + prefetched weight for one row (2 rows ahead)
    auto issue = [&](f4 (&vals)[V4], float& w, int& l, int r) {
        const f4* row4 = reinterpret_cast<const f4*>(f + (size_t)r * (size_t)K);
        #pragma unroll
        for (int t = 0; t < V4; ++t) {
            int j4 = lane + 64 * t;
            vals[t] = (j4 < K4) ? __builtin_nontemporal_load(&row4[j4]) : (f4)(0.f);
        }
        w = w_row[r];
        l = labels[r];
    };

    // consume one row
    auto process = [&](f4 (&vals)[V4], float w, int l) {
        float e = 0.f;
        #pragma unroll
        for (int t = 0; t < V4; ++t) {
            int j4 = lane + 64 * t;
            if (j4 < K4) {
                e += __expf(vals[t].x) + __expf(vals[t].y) +
                     __expf(vals[t].z) + __expf(vals[t].w);
                gacc[t].x = fmaf(w, vals[t].x, gacc[t].x);
                gacc[t].y = fmaf(w, vals[t].y, gacc[t].y);
                gacc[t].z = fmaf(w, vals[t].z, gacc[t].z);
                gacc[t].w = fmaf(w, vals[t].w, gacc[t].w);
            }
        }
        e = wave_reduce_sum(e);
        float lse = __logf(e);
        const int j4l = l >> 2;
        const int ll = j4l & 63;
        const int tl = j4l >> 6;
        const int cl = l & 3;
        #pragma unroll
        for (int t = 0; t < V4; ++t) {
            if (lane == ll && t == tl) {  // static t index (no scratch)
                float vl = (cl == 0) ? vals[t].x
                         : (cl == 1) ? vals[t].y
                         : (cl == 2) ? vals[t].z : vals[t].w;
                atomicAdd(&d_sh[l], lse - vl);
            }
        }
        if (lane == 0) s_reg = fmaf(w, lse, s_reg);
    };

    // strided rows: r = gwid, gwid+nwaves, ...  (adjacent waves -> adjacent rows)
    int rA = gwid;
    int rB = rA + nwaves;
    int rC = rB + nwaves;
    if (rA < N) {
        issue(valsA, wA, lA, rA);
        if (rB < N) issue(valsB, wB, lB, rB);
        while (true) {
            if (rC < N) issue(valsC, wC, lC, rC);
            process(valsA, wA, lA);
            rA = rC + nwaves;  // next row for the A slot
            if (rB >= N) break;
            if (rA < N) issue(valsA, wA, lA, rA);
            process(valsB, wB, lB);
            rB = rA + nwaves;
            if (rC >= N) break;
            if (rB < N) issue(valsB, wB, lB, rB);
            process(valsC, wC, lC);
            rC = rB + nwaves;
            if (rA >= N) break;
        }
    }

    // ---- block flush ----
    if (lane == 0) s_sh[wid] = s_reg;
    #pragma unroll
    for (int t = 0; t < V4; ++t) {
        int j4 = lane + 64 * t;
        if (j4 < K4) {
            atomicAdd(&g_sh[4 * j4 + 0], gacc[t].x);
            atomicAdd(&g_sh[4 * j4 + 1], gacc[t].y);
            atomicAdd(&g_sh[4 * j4 + 2], gacc[t].z);
            atomicAdd(&g_sh[4 * j4 + 3], gacc[t].w);
        }
    }
    __syncthreads();
    const int part = (blockIdx.x & 7) * 1024;
    for (int j = tid; j < K; j += 256) {
        atomicAdd(&g_multi[part + j], g_sh[j]);
        atomicAdd(&d_multi[part + j], d_sh[j]);
    }
    if (tid == 0) {
        atomicAdd(S_acc, s_sh[0] + s_sh[1] + s_sh[2] + s_sh[3]);
    }

    // ---- last-finished block finalizes (output-deterministic) ----
    __threadfence();
    if (tid == 0) {
        int done = atomicAdd(done_ctr, 1);
        is_last = (done == (int)gridDim.x - 1);
    }
    __syncthreads();
    if (is_last) {
        __threadfence();
        const float S = S_acc[0];
        float lvsum = 0.f;
        #pragma unroll
        for (int q = 0; q < 4; ++q) {
            int j = tid + q * 256;
            if (j < K) {
                float gj = 0.f, dj = 0.f;
                #pragma unroll
                for (int c = 0; c < 8; ++c) {
                    gj += g_multi[c * 1024 + j];
                    dj += d_multi[c * 1024 + j];
                }
                float cnt = counts[j];
                float dm = (cnt > 0.f) ? dj / cnt : 0.f;
                float val = S - gj - (float)(K - 1) * ccp[j] * dm;
                lvsum += val;
                out[1 + j] = cnt * val;
            }
        }
        float v = wave_reduce_sum(lvsum);
        if (lane == 0) red[wid] = v;
        __syncthreads();
        if (tid == 0) out[0] = red[0] + red[1] + red[2] + red[3];
    }
}

extern "C" void kernel_launch(void* const* d_in, const int* in_sizes, int n_in,
                              void* d_out, int out_size, void* d_ws, size_t ws_size,
                              hipStream_t stream) {
    const float* f = (const float*)d_in[0];
    const float* ccp = (const float*)d_in[1];
    const int* labels = (const int*)d_in[2];
    const int K = in_sizes[1];  // 1000
    const int N = in_sizes[2];  // 131072

    float* ws = (float*)d_ws;
    float* counts = ws;                 // 1024
    float* g_multi = ws + 1024;         // 8 x 1024
    float* d_multi = ws + 9216;         // 8 x 1024
    float* S_acc = ws + 17408;          // 1
    int* done_ctr = (int*)(ws + 17409); // 1
    float* w_row = ws + 32768;          // N
    float* out = (float*)d_out;         // 1 + K

    (void)hipMemsetAsync(d_ws, 0, (size_t)17410 * sizeof(float), stream);

    count_kernel<<<256, 256, 0, stream>>>(labels, counts, N, K);
    wprep_kernel<<<(N + 255) / 256, 256, 0, stream>>>(labels, ccp, counts, w_row, N);
    main_kernel<4><<<1024, 256, 0, stream>>>(f, labels, w_row, ccp, counts,
                                             g_multi, d_multi, S_acc, done_ctr,
                                             out, N, K);
}

// Round 12
// 122.165 us; speedup vs baseline: 2.4912x; 2.4912x over previous
//
#include <hip/hip_runtime.h>
#include <math.h>

// N=131072 rows, K=1000 classes, f fp32 ~ N(0,1).
// out[0] = final_loss, out[1..K] = weighted[K]  (fp32)
//
// lse_i = log(sum_j exp(f_ij))   [no max subtraction: |f| <= ~6, exp<=~400, safe fp32]
// w_i   = ccp[l_i]/counts[l_i];  S = sum_i w_i*lse_i
// g[j]  = sum_i w_i*f[i,j];      d[k] = sum_{l_i=k}(lse_i - f[i,k])
// loss_vector[j] = S - g[j] - (K-1)*ccp[j]*d[j]/counts[j]
// final_loss = sum_j lv[j]; weighted[j] = counts[j]*lv[j]
//
// R12 = EXACT R6 kernels (canonical 116.2us: wprep + strided + 3-deep + nt;
// separate finalize launch). Single delta: main grid 1024 -> 2048 blocks
// (16 -> 32 waves/CU) for more latency-hiding.
// R10/R11 lesson: last-block finalize tail wrecked the hot loop's regalloc
// (VGPR 48, pipeline destroyed, 3x slower) -- keep finalize as its own kernel.

typedef float f4 __attribute__((ext_vector_type(4)));

__device__ inline float wave_reduce_sum(float v) {
    #pragma unroll
    for (int off = 32; off > 0; off >>= 1)
        v += __shfl_xor(v, off, 64);
    return v;
}

// ---------------- kernel 1: per-class counts ----------------
__global__ __launch_bounds__(256) void count_kernel(const int* __restrict__ labels,
                                                    float* __restrict__ counts,
                                                    int N, int K) {
    __shared__ int h[1024];
    for (int j = threadIdx.x; j < 1024; j += blockDim.x) h[j] = 0;
    __syncthreads();
    for (int i = blockIdx.x * blockDim.x + threadIdx.x; i < N;
         i += gridDim.x * blockDim.x) {
        atomicAdd(&h[labels[i]], 1);
    }
    __syncthreads();
    for (int j = threadIdx.x; j < K; j += blockDim.x) {
        int c = h[j];
        if (c) atomicAdd(&counts[j], (float)c);
    }
}

// ---------------- kernel 2: per-row weight w[i] = ccp[l]/counts[l] ----------------
__global__ __launch_bounds__(256) void wprep_kernel(const int* __restrict__ labels,
                                                    const float* __restrict__ ccp,
                                                    const float* __restrict__ counts,
                                                    float* __restrict__ w_row, int N) {
    int i = blockIdx.x * blockDim.x + threadIdx.x;
    if (i < N) {
        int l = labels[i];
        w_row[i] = ccp[l] / counts[l];
    }
}

// ---------------- kernel 3: main streaming pass ----------------
// One wave per row, STRIDED row assignment (r += nwaves); 3-row software
// pipeline with named A/B/C register sets (static indexing, no scratch).
template <int V4>
__global__ __launch_bounds__(256) void main_kernel(
    const float* __restrict__ f, const int* __restrict__ labels,
    const float* __restrict__ w_row,
    float* __restrict__ g_multi, float* __restrict__ d_multi,
    float* __restrict__ S_acc, int N, int K) {
    __shared__ float g_sh[1024];
    __shared__ float d_sh[1024];
    __shared__ float s_sh[4];

    const int tid = threadIdx.x;
    const int lane = tid & 63;
    const int wid = tid >> 6;
    const int gwid = blockIdx.x * 4 + wid;
    const int nwaves = gridDim.x * 4;
    const int K4 = K >> 2;  // K % 4 == 0

    for (int j = tid; j < 1024; j += 256) { g_sh[j] = 0.f; d_sh[j] = 0.f; }
    __syncthreads();

    f4 gacc[V4];
    #pragma unroll
    for (int t = 0; t < V4; ++t) gacc[t] = (f4)(0.f);
    float s_reg = 0.f;  // lane 0: sum of w*lse over this wave's rows

    f4 valsA[V4], valsB[V4], valsC[V4];
    float wA = 0.f, wB = 0.f, wC = 0.f;
    int lA = 0, lB = 0, lC = 0;

    // issue loads + prefetched weight for one row (2 rows ahead)
    auto issue = [&](f4 (&vals)[V4], float& w, int& l, int r) {
        const f4* row4 = reinterpret_cast<const f4*>(f + (size_t)r * (size_t)K);
        #pragma unroll
        for (int t = 0; t < V4; ++t) {
            int j4 = lane + 64 * t;
            vals[t] = (j4 < K4) ? __builtin_nontemporal_load(&row4[j4]) : (f4)(0.f);
        }
        w = w_row[r];
        l = labels[r];
    };

    // consume one row
    auto process = [&](f4 (&vals)[V4], float w, int l) {
        float e = 0.f;
        #pragma unroll
        for (int t = 0; t < V4; ++t) {
            int j4 = lane + 64 * t;
            if (j4 < K4) {
                e += __expf(vals[t].x) + __expf(vals[t].y) +
                     __expf(vals[t].z) + __expf(vals[t].w);
                gacc[t].x = fmaf(w, vals[t].x, gacc[t].x);
                gacc[t].y = fmaf(w, vals[t].y, gacc[t].y);
                gacc[t].z = fmaf(w, vals[t].z, gacc[t].z);
                gacc[t].w = fmaf(w, vals[t].w, gacc[t].w);
            }
        }
        e = wave_reduce_sum(e);
        float lse = __logf(e);
        const int j4l = l >> 2;
        const int ll = j4l & 63;
        const int tl = j4l >> 6;
        const int cl = l & 3;
        #pragma unroll
        for (int t = 0; t < V4; ++t) {
            if (lane == ll && t == tl) {  // static t index (no scratch)
                float vl = (cl == 0) ? vals[t].x
                         : (cl == 1) ? vals[t].y
                         : (cl == 2) ? vals[t].z : vals[t].w;
                atomicAdd(&d_sh[l], lse - vl);
            }
        }
        if (lane == 0) s_reg = fmaf(w, lse, s_reg);
    };

    // strided rows: r = gwid, gwid+nwaves, ...  (adjacent waves -> adjacent rows)
    int rA = gwid;
    int rB = rA + nwaves;
    int rC = rB + nwaves;
    if (rA < N) {
        issue(valsA, wA, lA, rA);
        if (rB < N) issue(valsB, wB, lB, rB);
        while (true) {
            if (rC < N) issue(valsC, wC, lC, rC);
            process(valsA, wA, lA);
            rA = rC + nwaves;  // next row for the A slot
            if (rB >= N) break;
            if (rA < N) issue(valsA, wA, lA, rA);
            process(valsB, wB, lB);
            rB = rA + nwaves;
            if (rC >= N) break;
            if (rB < N) issue(valsB, wB, lB, rB);
            process(valsC, wC, lC);
            rC = rB + nwaves;
            if (rA >= N) break;
        }
    }

    // ---- block flush ----
    if (lane == 0) s_sh[wid] = s_reg;
    #pragma unroll
    for (int t = 0; t < V4; ++t) {
        int j4 = lane + 64 * t;
        if (j4 < K4) {
            atomicAdd(&g_sh[4 * j4 + 0], gacc[t].x);
            atomicAdd(&g_sh[4 * j4 + 1], gacc[t].y);
            atomicAdd(&g_sh[4 * j4 + 2], gacc[t].z);
            atomicAdd(&g_sh[4 * j4 + 3], gacc[t].w);
        }
    }
    __syncthreads();
    const int part = (blockIdx.x & 7) * 1024;
    for (int j = tid; j < K; j += 256) {
        atomicAdd(&g_multi[part + j], g_sh[j]);
        atomicAdd(&d_multi[part + j], d_sh[j]);
    }
    if (tid == 0) {
        atomicAdd(S_acc, s_sh[0] + s_sh[1] + s_sh[2] + s_sh[3]);
    }
}

// ---------------- kernel 4: finalize (1 block) ----------------
__global__ __launch_bounds__(1024) void finalize_kernel(
    const float* __restrict__ ccp, const float* __restrict__ counts,
    const float* __restrict__ g_multi, const float* __restrict__ d_multi,
    const float* __restrict__ S_acc, float* __restrict__ out, int K) {
    __shared__ float red[16];
    const int j = threadIdx.x;
    const float S = S_acc[0];

    float lv = 0.f;
    if (j < K) {
        float gj = 0.f, dj = 0.f;
        #pragma unroll
        for (int c = 0; c < 8; ++c) {
            gj += g_multi[c * 1024 + j];
            dj += d_multi[c * 1024 + j];
        }
        float cnt = counts[j];
        float dm = (cnt > 0.f) ? dj / cnt : 0.f;
        float val = S - gj - (float)(K - 1) * ccp[j] * dm;
        lv = val;
        out[1 + j] = cnt * val;
    }

    float v = wave_reduce_sum(lv);
    const int lane = j & 63;
    const int wv = j >> 6;
    if (lane == 0) red[wv] = v;
    __syncthreads();
    if (j == 0) {
        float tot = 0.f;
        for (int w2 = 0; w2 < 16; ++w2) tot += red[w2];
        out[0] = tot;
    }
}

extern "C" void kernel_launch(void* const* d_in, const int* in_sizes, int n_in,
                              void* d_out, int out_size, void* d_ws, size_t ws_size,
                              hipStream_t stream) {
    const float* f = (const float*)d_in[0];
    const float* ccp = (const float*)d_in[1];
    const int* labels = (const int*)d_in[2];
    const int K = in_sizes[1];  // 1000
    const int N = in_sizes[2];  // 131072

    float* ws = (float*)d_ws;
    float* counts = ws;                 // [0, 1024)
    float* g_multi = ws + 1024;         // 8 x 1024
    float* d_multi = ws + 1024 + 8192;  // 8 x 1024
    float* S_acc = ws + 1024 + 16384;   // [1]
    float* w_row = ws + 32768;          // [N]
    float* out = (float*)d_out;         // [1 + K]

    (void)hipMemsetAsync(d_ws, 0, (size_t)32768 * sizeof(float), stream);

    count_kernel<<<256, 256, 0, stream>>>(labels, counts, N, K);
    wprep_kernel<<<(N + 255) / 256, 256, 0, stream>>>(labels, ccp, counts, w_row, N);
    main_kernel<4><<<2048, 256, 0, stream>>>(f, labels, w_row, g_multi, d_multi,
                                             S_acc, N, K);
    finalize_kernel<<<1, 1024, 0, stream>>>(ccp, counts, g_multi, d_multi, S_acc,
                                            out, K);
}

// Round 13
// 119.091 us; speedup vs baseline: 2.5555x; 1.0258x over previous
//
#include <hip/hip_runtime.h>
#include <math.h>

// N=131072 rows, K=1000 classes, f fp32 ~ N(0,1).
// out[0] = final_loss, out[1..K] = weighted[K]  (fp32)
//
// lse_i = log(sum_j exp(f_ij))   [no max subtraction: |f| <= ~6, exp<=~400, safe fp32]
// w_i   = ccp[l_i]/counts[l_i];  S = sum_i w_i*lse_i
// g[j]  = sum_i w_i*f[i,j];      d[k] = sum_{l_i=k}(lse_i - f[i,k])
// loss_vector[j] = S - g[j] - (K-1)*ccp[j]*d[j]/counts[j]
// final_loss = sum_j lv[j]; weighted[j] = counts[j]*lv[j]
//
// R13 = R6 hot loop (strided rows, 3-deep A/B/C pipeline, nt loads, grid 1024)
// with wprep DELETED: each block's prologue computes its own 128 rows'
// (w, label) pairs into LDS once (parallel gather, not per-row -> avoids the
// R8/R10 dependent-load serialization). Hot loop reads w,l from LDS.
// 5 -> 4 dispatches, -1MB HBM traffic, hot loop has zero non-row VMEM.

typedef float f4 __attribute__((ext_vector_type(4)));

__device__ inline float wave_reduce_sum(float v) {
    #pragma unroll
    for (int off = 32; off > 0; off >>= 1)
        v += __shfl_xor(v, off, 64);
    return v;
}

// ---------------- kernel 1: per-class counts ----------------
__global__ __launch_bounds__(256) void count_kernel(const int* __restrict__ labels,
                                                    float* __restrict__ counts,
                                                    int N, int K) {
    __shared__ int h[1024];
    for (int j = threadIdx.x; j < 1024; j += blockDim.x) h[j] = 0;
    __syncthreads();
    for (int i = blockIdx.x * blockDim.x + threadIdx.x; i < N;
         i += gridDim.x * blockDim.x) {
        atomicAdd(&h[labels[i]], 1);
    }
    __syncthreads();
    for (int j = threadIdx.x; j < K; j += blockDim.x) {
        int c = h[j];
        if (c) atomicAdd(&counts[j], (float)c);
    }
}

// ---------------- kernel 2: main streaming pass ----------------
// One wave per row, STRIDED row assignment (r += nwaves); 3-row software
// pipeline with named A/B/C register sets (static indexing, no scratch).
// MAXR = max rows per wave (N=131072, 4096 waves -> exactly 32).
template <int V4, int MAXR>
__global__ __launch_bounds__(256) void main_kernel(
    const float* __restrict__ f, const int* __restrict__ labels,
    const float* __restrict__ ccp, const float* __restrict__ counts,
    float* __restrict__ g_multi, float* __restrict__ d_multi,
    float* __restrict__ S_acc, int N, int K) {
    __shared__ float g_sh[1024];
    __shared__ float d_sh[1024];
    __shared__ float s_sh[4];
    __shared__ float w_sh[4 * MAXR];
    __shared__ int l_sh[4 * MAXR];

    const int tid = threadIdx.x;
    const int lane = tid & 63;
    const int wid = tid >> 6;
    const int gwid = blockIdx.x * 4 + wid;
    const int nwaves = gridDim.x * 4;
    const int K4 = K >> 2;  // K % 4 == 0

    for (int j = tid; j < 1024; j += 256) { g_sh[j] = 0.f; d_sh[j] = 0.f; }
    // ---- prologue: per-block (w, label) gather into LDS, once ----
    // entry e = (wv, i): row = bid*4 + wv + i*nwaves
    for (int e = tid; e < 4 * MAXR; e += 256) {
        const int wv = e / MAXR;
        const int i = e % MAXR;
        const int row = blockIdx.x * 4 + wv + i * nwaves;
        float w = 0.f;
        int l = 0;
        if (row < N) {
            l = labels[row];
            w = ccp[l] / counts[l];
        }
        w_sh[e] = w;
        l_sh[e] = l;
    }
    __syncthreads();

    f4 gacc[V4];
    #pragma unroll
    for (int t = 0; t < V4; ++t) gacc[t] = (f4)(0.f);
    float s_reg = 0.f;  // lane 0: sum of w*lse over this wave's rows

    f4 valsA[V4], valsB[V4], valsC[V4];
    float wA = 0.f, wB = 0.f, wC = 0.f;
    int lA = 0, lB = 0, lC = 0;

    // issue row loads + (w,l) from LDS for row-index i of this wave
    auto issue = [&](f4 (&vals)[V4], float& w, int& l, int r, int i) {
        const f4* row4 = reinterpret_cast<const f4*>(f + (size_t)r * (size_t)K);
        #pragma unroll
        for (int t = 0; t < V4; ++t) {
            int j4 = lane + 64 * t;
            vals[t] = (j4 < K4) ? __builtin_nontemporal_load(&row4[j4]) : (f4)(0.f);
        }
        w = w_sh[wid * MAXR + i];
        l = l_sh[wid * MAXR + i];
    };

    // consume one row
    auto process = [&](f4 (&vals)[V4], float w, int l) {
        float e = 0.f;
        #pragma unroll
        for (int t = 0; t < V4; ++t) {
            int j4 = lane + 64 * t;
            if (j4 < K4) {
                e += __expf(vals[t].x) + __expf(vals[t].y) +
                     __expf(vals[t].z) + __expf(vals[t].w);
                gacc[t].x = fmaf(w, vals[t].x, gacc[t].x);
                gacc[t].y = fmaf(w, vals[t].y, gacc[t].y);
                gacc[t].z = fmaf(w, vals[t].z, gacc[t].z);
                gacc[t].w = fmaf(w, vals[t].w, gacc[t].w);
            }
        }
        e = wave_reduce_sum(e);
        float lse = __logf(e);
        const int j4l = l >> 2;
        const int ll = j4l & 63;
        const int tl = j4l >> 6;
        const int cl = l & 3;
        #pragma unroll
        for (int t = 0; t < V4; ++t) {
            if (lane == ll && t == tl) {  // static t index (no scratch)
                float vl = (cl == 0) ? vals[t].x
                         : (cl == 1) ? vals[t].y
                         : (cl == 2) ? vals[t].z : vals[t].w;
                atomicAdd(&d_sh[l], lse - vl);
            }
        }
        if (lane == 0) s_reg = fmaf(w, lse, s_reg);
    };

    // strided rows: r = gwid + i*nwaves (adjacent waves -> adjacent rows)
    int rA = gwid, iA = 0;
    int rB = rA + nwaves, iB = 1;
    int rC = rB + nwaves, iC = 2;
    if (rA < N) {
        issue(valsA, wA, lA, rA, iA);
        if (rB < N) issue(valsB, wB, lB, rB, iB);
        while (true) {
            if (rC < N) issue(valsC, wC, lC, rC, iC);
            process(valsA, wA, lA);
            rA = rC + nwaves; iA = iC + 1;
            if (rB >= N) break;
            if (rA < N) issue(valsA, wA, lA, rA, iA);
            process(valsB, wB, lB);
            rB = rA + nwaves; iB = iA + 1;
            if (rC >= N) break;
            if (rB < N) issue(valsB, wB, lB, rB, iB);
            process(valsC, wC, lC);
            rC = rB + nwaves; iC = iB + 1;
            if (rA >= N) break;
        }
    }

    // ---- block flush ----
    if (lane == 0) s_sh[wid] = s_reg;
    #pragma unroll
    for (int t = 0; t < V4; ++t) {
        int j4 = lane + 64 * t;
        if (j4 < K4) {
            atomicAdd(&g_sh[4 * j4 + 0], gacc[t].x);
            atomicAdd(&g_sh[4 * j4 + 1], gacc[t].y);
            atomicAdd(&g_sh[4 * j4 + 2], gacc[t].z);
            atomicAdd(&g_sh[4 * j4 + 3], gacc[t].w);
        }
    }
    __syncthreads();
    const int part = (blockIdx.x & 7) * 1024;
    for (int j = tid; j < K; j += 256) {
        atomicAdd(&g_multi[part + j], g_sh[j]);
        atomicAdd(&d_multi[part + j], d_sh[j]);
    }
    if (tid == 0) {
        atomicAdd(S_acc, s_sh[0] + s_sh[1] + s_sh[2] + s_sh[3]);
    }
}

// ---------------- kernel 3: finalize (1 block) ----------------
__global__ __launch_bounds__(1024) void finalize_kernel(
    const float* __restrict__ ccp, const float* __restrict__ counts,
    const float* __restrict__ g_multi, const float* __restrict__ d_multi,
    const float* __restrict__ S_acc, float* __restrict__ out, int K) {
    __shared__ float red[16];
    const int j = threadIdx.x;
    const float S = S_acc[0];

    float lv = 0.f;
    if (j < K) {
        float gj = 0.f, dj = 0.f;
        #pragma unroll
        for (int c = 0; c < 8; ++c) {
            gj += g_multi[c * 1024 + j];
            dj += d_multi[c * 1024 + j];
        }
        float cnt = counts[j];
        float dm = (cnt > 0.f) ? dj / cnt : 0.f;
        float val = S - gj - (float)(K - 1) * ccp[j] * dm;
        lv = val;
        out[1 + j] = cnt * val;
    }

    float v = wave_reduce_sum(lv);
    const int lane = j & 63;
    const int wv = j >> 6;
    if (lane == 0) red[wv] = v;
    __syncthreads();
    if (j == 0) {
        float tot = 0.f;
        for (int w2 = 0; w2 < 16; ++w2) tot += red[w2];
        out[0] = tot;
    }
}

extern "C" void kernel_launch(void* const* d_in, const int* in_sizes, int n_in,
                              void* d_out, int out_size, void* d_ws, size_t ws_size,
                              hipStream_t stream) {
    const float* f = (const float*)d_in[0];
    const float* ccp = (const float*)d_in[1];
    const int* labels = (const int*)d_in[2];
    const int K = in_sizes[1];  // 1000
    const int N = in_sizes[2];  // 131072

    float* ws = (float*)d_ws;
    float* counts = ws;                 // [0, 1024)
    float* g_multi = ws + 1024;         // 8 x 1024
    float* d_multi = ws + 1024 + 8192;  // 8 x 1024
    float* S_acc = ws + 1024 + 16384;   // [1]
    float* out = (float*)d_out;         // [1 + K]

    (void)hipMemsetAsync(d_ws, 0, (size_t)(1024 + 16384 + 1) * sizeof(float), stream);

    count_kernel<<<256, 256, 0, stream>>>(labels, counts, N, K);
    // 1024 blocks x 4 waves = 4096 waves; N/4096 = 32 rows/wave = MAXR.
    main_kernel<4, 32><<<1024, 256, 0, stream>>>(f, labels, ccp, counts, g_multi,
                                                 d_multi, S_acc, N, K);
    finalize_kernel<<<1, 1024, 0, stream>>>(ccp, counts, g_multi, d_multi, S_acc,
                                            out, K);
}

// Round 14
// 116.422 us; speedup vs baseline: 2.6141x; 1.0229x over previous
//
#include <hip/hip_runtime.h>
#include <math.h>

// N=131072 rows, K=1000 classes, f fp32 ~ N(0,1).
// out[0] = final_loss, out[1..K] = weighted[K]  (fp32)
//
// lse_i = log(sum_j exp(f_ij))   [no max subtraction: |f| <= ~6, exp<=~400, safe fp32]
// w_i   = ccp[l_i]/counts[l_i];  S = sum_i w_i*lse_i
// g[j]  = sum_i w_i*f[i,j];      d[k] = sum_{l_i=k}(lse_i - f[i,k])
// loss_vector[j] = S - g[j] - (K-1)*ccp[j]*d[j]/counts[j]
// final_loss = sum_j lv[j]; weighted[j] = counts[j]*lv[j]
//
// FINAL = R6 canonical config (116.2us, proven twice):
//   - wprep kernel prefetches w_row (in-loop lookup = R8/R10 serialization trap)
//   - strided row assignment (chunked = R5 regression)
//   - 3-deep A/B/C software pipeline, static register sets
//   - nontemporal loads (+8% vs plain, R7 A/B)
//   - grid 1024x256 (2048 = R12 regression)
//   - separate finalize launch (tail-fold = R11 regalloc poison, VGPR 164->48)
// Main kernel ~5.2 TB/s effective = 83% of copy ceiling, matching the
// empirical MI355X streaming-reduction band (82-86%, learn_hip m146/m219/m238).

typedef float f4 __attribute__((ext_vector_type(4)));

__device__ inline float wave_reduce_sum(float v) {
    #pragma unroll
    for (int off = 32; off > 0; off >>= 1)
        v += __shfl_xor(v, off, 64);
    return v;
}

// ---------------- kernel 1: per-class counts ----------------
__global__ __launch_bounds__(256) void count_kernel(const int* __restrict__ labels,
                                                    float* __restrict__ counts,
                                                    int N, int K) {
    __shared__ int h[1024];
    for (int j = threadIdx.x; j < 1024; j += blockDim.x) h[j] = 0;
    __syncthreads();
    for (int i = blockIdx.x * blockDim.x + threadIdx.x; i < N;
         i += gridDim.x * blockDim.x) {
        atomicAdd(&h[labels[i]], 1);
    }
    __syncthreads();
    for (int j = threadIdx.x; j < K; j += blockDim.x) {
        int c = h[j];
        if (c) atomicAdd(&counts[j], (float)c);
    }
}

// ---------------- kernel 2: per-row weight w[i] = ccp[l]/counts[l] ----------------
__global__ __launch_bounds__(256) void wprep_kernel(const int* __restrict__ labels,
                                                    const float* __restrict__ ccp,
                                                    const float* __restrict__ counts,
                                                    float* __restrict__ w_row, int N) {
    int i = blockIdx.x * blockDim.x + threadIdx.x;
    if (i < N) {
        int l = labels[i];
        w_row[i] = ccp[l] / counts[l];
    }
}

// ---------------- kernel 3: main streaming pass ----------------
// One wave per row, STRIDED row assignment (r += nwaves); 3-row software
// pipeline with named A/B/C register sets (static indexing, no scratch).
template <int V4>
__global__ __launch_bounds__(256) void main_kernel(
    const float* __restrict__ f, const int* __restrict__ labels,
    const float* __restrict__ w_row,
    float* __restrict__ g_multi, float* __restrict__ d_multi,
    float* __restrict__ S_acc, int N, int K) {
    __shared__ float g_sh[1024];
    __shared__ float d_sh[1024];
    __shared__ float s_sh[4];

    const int tid = threadIdx.x;
    const int lane = tid & 63;
    const int wid = tid >> 6;
    const int gwid = blockIdx.x * 4 + wid;
    const int nwaves = gridDim.x * 4;
    const int K4 = K >> 2;  // K % 4 == 0

    for (int j = tid; j < 1024; j += 256) { g_sh[j] = 0.f; d_sh[j] = 0.f; }
    __syncthreads();

    f4 gacc[V4];
    #pragma unroll
    for (int t = 0; t < V4; ++t) gacc[t] = (f4)(0.f);
    float s_reg = 0.f;  // lane 0: sum of w*lse over this wave's rows

    f4 valsA[V4], valsB[V4], valsC[V4];
    float wA = 0.f, wB = 0.f, wC = 0.f;
    int lA = 0, lB = 0, lC = 0;

    // issue loads + prefetched weight for one row (2 rows ahead)
    auto issue = [&](f4 (&vals)[V4], float& w, int& l, int r) {
        const f4* row4 = reinterpret_cast<const f4*>(f + (size_t)r * (size_t)K);
        #pragma unroll
        for (int t = 0; t < V4; ++t) {
            int j4 = lane + 64 * t;
            vals[t] = (j4 < K4) ? __builtin_nontemporal_load(&row4[j4]) : (f4)(0.f);
        }
        w = w_row[r];
        l = labels[r];
    };

    // consume one row
    auto process = [&](f4 (&vals)[V4], float w, int l) {
        float e = 0.f;
        #pragma unroll
        for (int t = 0; t < V4; ++t) {
            int j4 = lane + 64 * t;
            if (j4 < K4) {
                e += __expf(vals[t].x) + __expf(vals[t].y) +
                     __expf(vals[t].z) + __expf(vals[t].w);
                gacc[t].x = fmaf(w, vals[t].x, gacc[t].x);
                gacc[t].y = fmaf(w, vals[t].y, gacc[t].y);
                gacc[t].z = fmaf(w, vals[t].z, gacc[t].z);
                gacc[t].w = fmaf(w, vals[t].w, gacc[t].w);
            }
        }
        e = wave_reduce_sum(e);
        float lse = __logf(e);
        const int j4l = l >> 2;
        const int ll = j4l & 63;
        const int tl = j4l >> 6;
        const int cl = l & 3;
        #pragma unroll
        for (int t = 0; t < V4; ++t) {
            if (lane == ll && t == tl) {  // static t index (no scratch)
                float vl = (cl == 0) ? vals[t].x
                         : (cl == 1) ? vals[t].y
                         : (cl == 2) ? vals[t].z : vals[t].w;
                atomicAdd(&d_sh[l], lse - vl);
            }
        }
        if (lane == 0) s_reg = fmaf(w, lse, s_reg);
    };

    // strided rows: r = gwid, gwid+nwaves, ...  (adjacent waves -> adjacent rows)
    int rA = gwid;
    int rB = rA + nwaves;
    int rC = rB + nwaves;
    if (rA < N) {
        issue(valsA, wA, lA, rA);
        if (rB < N) issue(valsB, wB, lB, rB);
        while (true) {
            if (rC < N) issue(valsC, wC, lC, rC);
            process(valsA, wA, lA);
            rA = rC + nwaves;  // next row for the A slot
            if (rB >= N) break;
            if (rA < N) issue(valsA, wA, lA, rA);
            process(valsB, wB, lB);
            rB = rA + nwaves;
            if (rC >= N) break;
            if (rB < N) issue(valsB, wB, lB, rB);
            process(valsC, wC, lC);
            rC = rB + nwaves;
            if (rA >= N) break;
        }
    }

    // ---- block flush ----
    if (lane == 0) s_sh[wid] = s_reg;
    #pragma unroll
    for (int t = 0; t < V4; ++t) {
        int j4 = lane + 64 * t;
        if (j4 < K4) {
            atomicAdd(&g_sh[4 * j4 + 0], gacc[t].x);
            atomicAdd(&g_sh[4 * j4 + 1], gacc[t].y);
            atomicAdd(&g_sh[4 * j4 + 2], gacc[t].z);
            atomicAdd(&g_sh[4 * j4 + 3], gacc[t].w);
        }
    }
    __syncthreads();
    const int part = (blockIdx.x & 7) * 1024;
    for (int j = tid; j < K; j += 256) {
        atomicAdd(&g_multi[part + j], g_sh[j]);
        atomicAdd(&d_multi[part + j], d_sh[j]);
    }
    if (tid == 0) {
        atomicAdd(S_acc, s_sh[0] + s_sh[1] + s_sh[2] + s_sh[3]);
    }
}

// ---------------- kernel 4: finalize (1 block) ----------------
__global__ __launch_bounds__(1024) void finalize_kernel(
    const float* __restrict__ ccp, const float* __restrict__ counts,
    const float* __restrict__ g_multi, const float* __restrict__ d_multi,
    const float* __restrict__ S_acc, float* __restrict__ out, int K) {
    __shared__ float red[16];
    const int j = threadIdx.x;
    const float S = S_acc[0];

    float lv = 0.f;
    if (j < K) {
        float gj = 0.f, dj = 0.f;
        #pragma unroll
        for (int c = 0; c < 8; ++c) {
            gj += g_multi[c * 1024 + j];
            dj += d_multi[c * 1024 + j];
        }
        float cnt = counts[j];
        float dm = (cnt > 0.f) ? dj / cnt : 0.f;
        float val = S - gj - (float)(K - 1) * ccp[j] * dm;
        lv = val;
        out[1 + j] = cnt * val;
    }

    float v = wave_reduce_sum(lv);
    const int lane = j & 63;
    const int wv = j >> 6;
    if (lane == 0) red[wv] = v;
    __syncthreads();
    if (j == 0) {
        float tot = 0.f;
        for (int w2 = 0; w2 < 16; ++w2) tot += red[w2];
        out[0] = tot;
    }
}

extern "C" void kernel_launch(void* const* d_in, const int* in_sizes, int n_in,
                              void* d_out, int out_size, void* d_ws, size_t ws_size,
                              hipStream_t stream) {
    const float* f = (const float*)d_in[0];
    const float* ccp = (const float*)d_in[1];
    const int* labels = (const int*)d_in[2];
    const int K = in_sizes[1];  // 1000
    const int N = in_sizes[2];  // 131072

    float* ws = (float*)d_ws;
    float* counts = ws;                 // [0, 1024)
    float* g_multi = ws + 1024;         // 8 x 1024
    float* d_multi = ws + 1024 + 8192;  // 8 x 1024
    float* S_acc = ws + 1024 + 16384;   // [1]
    float* w_row = ws + 32768;          // [N]
    float* out = (float*)d_out;         // [1 + K]

    (void)hipMemsetAsync(d_ws, 0, (size_t)32768 * sizeof(float), stream);

    count_kernel<<<256, 256, 0, stream>>>(labels, counts, N, K);
    wprep_kernel<<<(N + 255) / 256, 256, 0, stream>>>(labels, ccp, counts, w_row, N);
    main_kernel<4><<<1024, 256, 0, stream>>>(f, labels, w_row, g_multi, d_multi,
                                             S_acc, N, K);
    finalize_kernel<<<1, 1024, 0, stream>>>(ccp, counts, g_multi, d_multi, S_acc,
                                            out, K);
}